// Round 1
// baseline (507.842 us; speedup 1.0000x reference)
//
#include <hip/hip_runtime.h>

#define NT 16384   // tokens
#define DM 4096    // d_model
#define NE 64      // experts
#define TPB 64     // tokens per block (one per lane)
#define NW 8       // waves per block = K-split
#define KS (DM / NW)  // 512 K per wave
#define KC 32      // f32 chunk accumulated into f64

// Block: 512 threads = 8 waves. Lane <-> token (64 tokens/block), wave <-> K-slice.
// W loads are wave-uniform -> scalar loads; x loads are per-lane (strided rows, L1-cached).
// f64 accumulation of 32-wide f32 chunks keeps logit error ~2e-7 so top-k matches the
// numpy reference (fp32-sequential's ~4e-6 error risks index flips at near-ties).
__launch_bounds__(512, 2)
__global__ void moe_gate_main(const float* __restrict__ x,
                              const float* __restrict__ W,
                              float* __restrict__ out,
                              float* __restrict__ bsum) {
  __shared__ float buf[NW][TPB][NE + 1];  // +1 pad: conflict-free dump/merge. 130 KiB.
  const int tid  = threadIdx.x;
  const int lane = tid & 63;
  const int wv   = __builtin_amdgcn_readfirstlane(tid >> 6);
  const int blk  = blockIdx.x;
  const int tok  = blk * TPB + lane;
  const int k0   = wv * KS;

  double acc[NE];
#pragma unroll
  for (int e = 0; e < NE; ++e) acc[e] = 0.0;

  const float* xp = x + (size_t)tok * DM + k0;
  for (int kc = 0; kc < KS; kc += KC) {
    float xv[KC];
#pragma unroll
    for (int j = 0; j < KC; j += 4) {
      const float4 t = *reinterpret_cast<const float4*>(xp + kc + j);
      xv[j] = t.x; xv[j + 1] = t.y; xv[j + 2] = t.z; xv[j + 3] = t.w;
    }
#pragma unroll
    for (int e = 0; e < NE; ++e) {
      const float* wr = W + (size_t)e * DM + k0 + kc;  // wave-uniform -> s_load
      float cs = 0.f;
#pragma unroll
      for (int j = 0; j < KC; ++j) cs = fmaf(xv[j], wr[j], cs);
      acc[e] += (double)cs;
    }
  }

  // dump per-wave K-partials (f32 is plenty for the merge)
#pragma unroll
  for (int e = 0; e < NE; ++e) buf[wv][lane][e] = (float)acc[e];
  __syncthreads();

  // Epilogue: wave wv handles tokens [wv*8, wv*8+8); lane <-> expert now.
  float esum = 0.f;  // per-lane (=expert) sum of softmax scores over my 8 tokens
  for (int ti = 0; ti < 8; ++ti) {
    const int t = wv * 8 + ti;
    float lg = 0.f;
#pragma unroll
    for (int w = 0; w < NW; ++w) lg += buf[w][t][lane];

    // softmax over 64 lanes
    float m = lg;
#pragma unroll
    for (int off = 32; off; off >>= 1) m = fmaxf(m, __shfl_xor(m, off, 64));
    const float p = __expf(lg - m);
    float Z = p;
#pragma unroll
    for (int off = 32; off; off >>= 1) Z += __shfl_xor(Z, off, 64);
    const float s = p / Z;
    esum += s;

    // top-1 (lexicographic max: value desc, index asc — matches lax.top_k ties)
    float v1 = s; int i1 = lane;
#pragma unroll
    for (int off = 32; off; off >>= 1) {
      const float ov = __shfl_xor(v1, off, 64);
      const int   oi = __shfl_xor(i1, off, 64);
      if (ov > v1 || (ov == v1 && oi < i1)) { v1 = ov; i1 = oi; }
    }
    // top-2: mask out winner (scores >= 0, so -1 acts as -inf)
    float sv = (lane == i1) ? -1.f : s;
    float v2 = sv; int i2 = lane;
#pragma unroll
    for (int off = 32; off; off >>= 1) {
      const float ov = __shfl_xor(v2, off, 64);
      const int   oi = __shfl_xor(i2, off, 64);
      if (ov > v2 || (ov == v2 && oi < i2)) { v2 = ov; i2 = oi; }
    }

    if (lane == 0) {
      const int gt = blk * TPB + t;
      const float inv = 1.f / (v1 + v2);
      out[2 * gt]              = v1 * inv;
      out[2 * gt + 1]          = v2 * inv;
      out[2 * NT + 2 * gt]     = (float)i1;
      out[2 * NT + 2 * gt + 1] = (float)i2;
    }
  }

  // per-block expert score sums (deterministic: tree reduce, no atomics)
  __syncthreads();  // done reading buf
  float* ps = &buf[0][0][0];  // reuse LDS as [NW][64]
  ps[wv * 64 + lane] = esum;
  __syncthreads();
  if (wv == 0) {
    float tot = 0.f;
#pragma unroll
    for (int w = 0; w < NW; ++w) tot += ps[w * 64 + lane];
    bsum[blk * 64 + lane] = tot;
  }
}

// Reduce 256 per-block expert sums -> load balancing loss
__global__ void moe_gate_loss(const float* __restrict__ bsum,
                              float* __restrict__ out) {
  __shared__ float red[4][64];
  const int e = threadIdx.x & 63;
  const int g = threadIdx.x >> 6;
  float s = 0.f;
  for (int b = g; b < 256; b += 4) s += bsum[b * 64 + e];
  red[g][e] = s;
  __syncthreads();
  if (threadIdx.x < 64) {
    const float tot = red[0][e] + red[1][e] + red[2][e] + red[3][e];
    const float p = tot * (1.f / (float)NT);
    float term = p * logf(p + 1e-8f);
#pragma unroll
    for (int off = 32; off; off >>= 1) term += __shfl_xor(term, off, 64);
    if (e == 0) out[4 * NT] = term;  // out[65536]
  }
}

extern "C" void kernel_launch(void* const* d_in, const int* in_sizes, int n_in,
                              void* d_out, int out_size, void* d_ws, size_t ws_size,
                              hipStream_t stream) {
  const float* x = (const float*)d_in[0];   // [16384, 4096]
  const float* W = (const float*)d_in[1];   // [64, 4096]
  float* out = (float*)d_out;               // scores[32768] | idx[32768] | loss[1]
  float* bsum = (float*)d_ws;               // [256][64] per-block expert sums (64 KiB)

  hipLaunchKernelGGL(moe_gate_main, dim3(NT / TPB), dim3(512), 0, stream, x, W, out, bsum);
  hipLaunchKernelGGL(moe_gate_loss, dim3(1), dim3(256), 0, stream, bsum, out);
}

// Round 2
// 288.720 us; speedup vs baseline: 1.7589x; 1.7589x over previous
//
#include <hip/hip_runtime.h>

#define NT 16384   // tokens
#define DM 4096    // d_model
#define NE 64      // experts
#define TPB 64     // tokens per block (one per lane)
#define NWAVE 8    // waves per block
#define EPW 8      // experts per wave (8 waves x 8 experts = 64)
#define BK 64      // K per LDS tile
#define NTILE (DM / BK)
#define TP 65      // padded token stride in LDS (65: write/read both <=2-way -> free)

// Block: 512 threads. lane <-> token (64 tokens/block); wave w <-> experts [8w,8w+8).
// W loads are wave-uniform -> scalar s_load (no VALU/VMEM cost). x staged coalesced
// global->LDS [k][token], double-buffered. f32 accumulation per 64-K tile drained
// into f64 (round-1-validated accuracy scheme, absmax 0).
__launch_bounds__(512, 2)
__global__ void moe_gate_main(const float* __restrict__ x,
                              const float* __restrict__ W,
                              float* __restrict__ out,
                              float* __restrict__ bsum) {
  __shared__ float xs[2][BK][TP];      // 33.3 KiB
  __shared__ float lg_s[TPB][NE + 1];  // 16.6 KiB
  __shared__ float esums[NWAVE][NE];   // 2 KiB

  const int tid  = threadIdx.x;
  const int lane = tid & 63;
  const int wv   = __builtin_amdgcn_readfirstlane(tid >> 6);
  const int blk  = blockIdx.x;

  // staging role: 8 threads per token row, each loads 8 consecutive floats (2x float4)
  const int srow = tid >> 3;         // token row within block (0..63)
  const int scol = (tid & 7) * 8;    // k offset within tile
  const float* xg = x + (size_t)(blk * TPB + srow) * DM + scol;

  float4 f0 = *reinterpret_cast<const float4*>(xg);
  float4 f1 = *reinterpret_cast<const float4*>(xg + 4);

  double accd[EPW];
#pragma unroll
  for (int j = 0; j < EPW; ++j) accd[j] = 0.0;

  const float* Wp = W + (size_t)(wv * EPW) * DM;  // wave-uniform base

  int cur = 0;
  for (int tile = 0; tile < NTILE; ++tile) {
    // write staged fragment, transposed -> xs[cur][k][tok]
    xs[cur][scol + 0][srow] = f0.x;
    xs[cur][scol + 1][srow] = f0.y;
    xs[cur][scol + 2][srow] = f0.z;
    xs[cur][scol + 3][srow] = f0.w;
    xs[cur][scol + 4][srow] = f1.x;
    xs[cur][scol + 5][srow] = f1.y;
    xs[cur][scol + 6][srow] = f1.z;
    xs[cur][scol + 7][srow] = f1.w;
    __syncthreads();

    // prefetch next tile (consumed at next iteration's ds_write; hides under compute)
    if (tile + 1 < NTILE) {
      const float* xn = xg + (size_t)(tile + 1) * BK;
      f0 = *reinterpret_cast<const float4*>(xn);
      f1 = *reinterpret_cast<const float4*>(xn + 4);
    }

    // compute this tile: 8 experts, 64 k, x from LDS, W via scalar loads
    float accf[EPW];
#pragma unroll
    for (int j = 0; j < EPW; ++j) accf[j] = 0.f;

    const float* Wk = Wp + tile * BK;
#pragma unroll 8
    for (int k = 0; k < BK; ++k) {
      const float xv = xs[cur][k][lane];
#pragma unroll
      for (int j = 0; j < EPW; ++j)
        accf[j] = fmaf(xv, Wk[(size_t)j * DM + k], accf[j]);
    }
#pragma unroll
    for (int j = 0; j < EPW; ++j) accd[j] += (double)accf[j];

    cur ^= 1;
    // no trailing barrier needed: next iter writes the other buffer; the
    // barrier at the top of iter i+1 orders writes(buf^1) vs reads(buf^1) at i+2.
  }

  // dump logits -> lg_s[tok][expert]
#pragma unroll
  for (int j = 0; j < EPW; ++j) lg_s[lane][wv * EPW + j] = (float)accd[j];
  __syncthreads();

  // Epilogue: wave wv handles tokens [wv*8, wv*8+8); lane <-> expert now.
  float esum = 0.f;
  for (int ti = 0; ti < 8; ++ti) {
    const int t = wv * 8 + ti;
    const float lg = lg_s[t][lane];

    // softmax over 64 lanes
    float m = lg;
#pragma unroll
    for (int off = 32; off; off >>= 1) m = fmaxf(m, __shfl_xor(m, off, 64));
    const float p = __expf(lg - m);
    float Z = p;
#pragma unroll
    for (int off = 32; off; off >>= 1) Z += __shfl_xor(Z, off, 64);
    const float s = p / Z;
    esum += s;

    // top-1 (value desc, index asc — matches lax.top_k tie-break)
    float v1 = s; int i1 = lane;
#pragma unroll
    for (int off = 32; off; off >>= 1) {
      const float ov = __shfl_xor(v1, off, 64);
      const int   oi = __shfl_xor(i1, off, 64);
      if (ov > v1 || (ov == v1 && oi < i1)) { v1 = ov; i1 = oi; }
    }
    // top-2: mask winner (scores >= 0, so -1 acts as -inf)
    float sv = (lane == i1) ? -1.f : s;
    float v2 = sv; int i2 = lane;
#pragma unroll
    for (int off = 32; off; off >>= 1) {
      const float ov = __shfl_xor(v2, off, 64);
      const int   oi = __shfl_xor(i2, off, 64);
      if (ov > v2 || (ov == v2 && oi < i2)) { v2 = ov; i2 = oi; }
    }

    if (lane == 0) {
      const int gt = blk * TPB + t;
      const float inv = 1.f / (v1 + v2);
      out[2 * gt]              = v1 * inv;
      out[2 * gt + 1]          = v2 * inv;
      out[2 * NT + 2 * gt]     = (float)i1;
      out[2 * NT + 2 * gt + 1] = (float)i2;
    }
  }

  // per-block expert score sums (deterministic tree reduce, no atomics)
  esums[wv][lane] = esum;
  __syncthreads();
  if (wv == 0) {
    float tot = 0.f;
#pragma unroll
    for (int w = 0; w < NWAVE; ++w) tot += esums[w][lane];
    bsum[blk * NE + lane] = tot;
  }
}

// Reduce 256 per-block expert sums -> load balancing loss
__global__ void moe_gate_loss(const float* __restrict__ bsum,
                              float* __restrict__ out) {
  __shared__ float red[4][64];
  const int e = threadIdx.x & 63;
  const int g = threadIdx.x >> 6;
  float s = 0.f;
  for (int b = g; b < 256; b += 4) s += bsum[b * 64 + e];
  red[g][e] = s;
  __syncthreads();
  if (threadIdx.x < 64) {
    const float tot = red[0][e] + red[1][e] + red[2][e] + red[3][e];
    const float p = tot * (1.f / (float)NT);
    float term = p * logf(p + 1e-8f);
#pragma unroll
    for (int off = 32; off; off >>= 1) term += __shfl_xor(term, off, 64);
    if (e == 0) out[4 * NT] = term;  // out[65536]
  }
}

extern "C" void kernel_launch(void* const* d_in, const int* in_sizes, int n_in,
                              void* d_out, int out_size, void* d_ws, size_t ws_size,
                              hipStream_t stream) {
  const float* x = (const float*)d_in[0];   // [16384, 4096]
  const float* W = (const float*)d_in[1];   // [64, 4096]
  float* out = (float*)d_out;               // scores[32768] | idx[32768] | loss[1]
  float* bsum = (float*)d_ws;               // [256][64] per-block expert sums

  hipLaunchKernelGGL(moe_gate_main, dim3(NT / TPB), dim3(512), 0, stream, x, W, out, bsum);
  hipLaunchKernelGGL(moe_gate_loss, dim3(1), dim3(256), 0, stream, bsum, out);
}